// Round 16
// baseline (555.000 us; speedup 1.0000x reference)
//
#include <hip/hip_runtime.h>
#include <hip/hip_cooperative_groups.h>
#include <hip/hip_bf16.h>
#include <hip/hip_fp16.h>
#include <math.h>

namespace cg = cooperative_groups;

constexpr int NN = 100000;
constexpr int EE = 1000000;
constexpr int RRR = 3;
constexpr int DIN = 128;
constexpr int DOUT = 64;
constexpr float SLOPE = 0.2f;
constexpr int NR = RRR * NN;                    // 300000 segments (relation-major)
constexpr int BSEG = 256;                       // segments per bucket
constexpr int NBUCK = (NR + BSEG - 1) / BSEG;   // 1172
constexpr int BCAP = 4096;                      // max edges/bucket
constexpr int CHUNK_E = 4096;                   // edges per chunk-block
constexpr int NCH_PER_R = (EE + CHUNK_E - 1) / CHUNK_E;   // 245
constexpr int NCH = RRR * NCH_PER_R;            // 735
constexpr int MT = NBUCK * NCH;                 // 861420
constexpr int SCAN_CHUNK = 1024;
constexpr int NSCB = (MT + SCAN_CHUNK - 1) / SCAN_CHUNK;  // 842
constexpr int GEMM_BLKS = (NN + 63) / 64;       // 1563

using f16x8 = __attribute__((ext_vector_type(8))) _Float16;
using f32x4 = __attribute__((ext_vector_type(4))) float;

// ---- DPP helpers: data movement on VALU pipe (no LDS round trip) ----
template<int CTRL>
__device__ __forceinline__ float dppf(float v) {
    return __int_as_float(__builtin_amdgcn_update_dpp(
        __float_as_int(v), __float_as_int(v), CTRL, 0xf, 0xf, false));
}
__device__ __forceinline__ float dpp_allred_add16(float v) {
    v += dppf<0xB1>(v);    // quad_perm xor1
    v += dppf<0x4E>(v);    // quad_perm xor2
    v += dppf<0x141>(v);   // row_half_mirror
    v += dppf<0x140>(v);   // row_mirror
    return v;
}

// ---------------- W -> MFMA B-fragment pack (fp16) + bias-sum precompute ----------------
__global__ __launch_bounds__(256) void pack_W(
    const float* __restrict__ W1, const float* __restrict__ W2,
    const float* __restrict__ b1, const float* __restrict__ b2,
    __half* __restrict__ Wp1, __half* __restrict__ Wp2,
    float* __restrict__ bs1, float* __restrict__ bs2)
{
    int r = blockIdx.x;  // 0..2
    for (int i = threadIdx.x; i < 4 * 4 * 512; i += 256) {    // W1: KS=4
        int j = i & 7, lane = (i >> 3) & 63, nt = (i >> 9) & 3, ks = i >> 11;
        int k = ks * 32 + (lane >> 4) * 8 + j, c = nt * 16 + (lane & 15);
        Wp1[((size_t)r * 16 + ks * 4 + nt) * 512 + lane * 8 + j] = __float2half(W1[(r * DIN + k) * 64 + c]);
    }
    for (int i = threadIdx.x; i < 2 * 4 * 512; i += 256) {    // W2: KS=2
        int j = i & 7, lane = (i >> 3) & 63, nt = (i >> 9) & 3, ks = i >> 11;
        int k = ks * 32 + (lane >> 4) * 8 + j, c = nt * 16 + (lane & 15);
        Wp2[((size_t)r * 8 + ks * 4 + nt) * 512 + lane * 8 + j] = __float2half(W2[(r * DOUT + k) * 64 + c]);
    }
    if (r == 0) {
        for (int c = threadIdx.x; c < 64; c += 256) {
            bs1[c] = (b1[c] + b1[64 + c] + b1[128 + c]) * (1.f / 3.f);
            bs2[c] = (b2[c] + b2[64 + c] + b2[128 + c]) * (1.f / 3.f);
        }
    }
}

// ---------------- shared GEMM body (MFMA, all 3 relations per block) ----------------
template<int K, typename AT>
__device__ __forceinline__ void gemm_body(
    int gbid,                        // gemm block id: rows gbid*64..+63
    const AT* __restrict__ xin,      // [NN, K]
    const __half* __restrict__ Wp,   // packed [R][K/32][4][512]
    const float* __restrict__ asrc, const float* __restrict__ adst,  // [R,64]
    __half* __restrict__ h,          // [R, NN, 64] fp16
    float* __restrict__ als, float* __restrict__ ald)                // [R, NN]
{
    constexpr int KS = K / 32;
    __shared__ float outb[64 * 65];
    const int t = threadIdx.x;
    const int lane = t & 63;
    const int w = t >> 6;
    const int row0 = gbid * 64;

    const int kgrp = lane >> 4;                  // 0..3
    const int l15 = lane & 15;
    int arow = row0 + w * 16 + l15; if (arow >= NN) arow = NN - 1;   // tail clamp (loads only)

    // ---- load A fragments once ----
    f16x8 a[KS];
    if constexpr (sizeof(AT) == 2) {
        const __half* ab = (const __half*)xin + (size_t)arow * K + kgrp * 8;
#pragma unroll
        for (int ks = 0; ks < KS; ++ks) a[ks] = *(const f16x8*)(ab + ks * 32);
    } else {
        const float* ab = (const float*)xin + (size_t)arow * K + kgrp * 8;
#pragma unroll
        for (int ks = 0; ks < KS; ++ks) {
            float4 lo = *(const float4*)(ab + ks * 32);
            float4 hi = *(const float4*)(ab + ks * 32 + 4);
            union { f16x8 v; __half2 p[4]; } u;
            u.p[0] = __floats2half2_rn(lo.x, lo.y);
            u.p[1] = __floats2half2_rn(lo.z, lo.w);
            u.p[2] = __floats2half2_rn(hi.x, hi.y);
            u.p[3] = __floats2half2_rn(hi.z, hi.w);
            a[ks] = u.v;
        }
    }

    const int nrows = (NN - row0 < 64) ? (NN - row0) : 64;

#pragma unroll
    for (int r = 0; r < RRR; ++r) {
        const __half* wbase = Wp + ((size_t)r * KS * 4) * 512 + lane * 8;
        f32x4 acc[4] = {};
#pragma unroll
        for (int ks = 0; ks < KS; ++ks) {
#pragma unroll
            for (int nt = 0; nt < 4; ++nt) {
                f16x8 b = *(const f16x8*)(wbase + (size_t)(ks * 4 + nt) * 512);
                acc[nt] = __builtin_amdgcn_mfma_f32_16x16x32_f16(a[ks], b, acc[nt], 0, 0, 0);
            }
        }

        // als/ald: lane holds cols {l15+16*nt} of rows row0+w*16+kgrp*4+i
        {
            float ps[4] = {0.f, 0.f, 0.f, 0.f}, pd[4] = {0.f, 0.f, 0.f, 0.f};
#pragma unroll
            for (int nt = 0; nt < 4; ++nt) {
                int c = l15 + 16 * nt;
                float a_ = asrc[r * 64 + c], d_ = adst[r * 64 + c];
#pragma unroll
                for (int i = 0; i < 4; ++i) {
                    ps[i] = fmaf(acc[nt][i], a_, ps[i]);
                    pd[i] = fmaf(acc[nt][i], d_, pd[i]);
                }
            }
#pragma unroll
            for (int o = 8; o; o >>= 1) {
#pragma unroll
                for (int i = 0; i < 4; ++i) {
                    ps[i] += __shfl_xor(ps[i], o);
                    pd[i] += __shfl_xor(pd[i], o);
                }
            }
            if (l15 == 0) {
#pragma unroll
                for (int i = 0; i < 4; ++i) {
                    int row = row0 + w * 16 + kgrp * 4 + i;
                    if (row < NN) { als[r * NN + row] = ps[i]; ald[r * NN + row] = pd[i]; }
                }
            }
        }

        // stage C to LDS, then coalesced fp16 write
#pragma unroll
        for (int nt = 0; nt < 4; ++nt)
#pragma unroll
            for (int i = 0; i < 4; ++i)
                outb[(w * 16 + kgrp * 4 + i) * 65 + l15 + 16 * nt] = acc[nt][i];
        __syncthreads();

        __half2* h2 = (__half2*)(h + ((size_t)r * NN + row0) * 64);
        for (int idx = t; idx < nrows * 32; idx += 256) {
            int row = idx >> 5, cc = idx & 31;
            h2[row * 32 + cc] = __floats2half2_rn(outb[row * 65 + cc * 2], outb[row * 65 + cc * 2 + 1]);
        }
        __syncthreads();
    }
}

__device__ __forceinline__ void hist_body(
    int hb,                          // hist block id 0..NCH-1
    const int* __restrict__ ei0, const int* __restrict__ ei1, const int* __restrict__ ei2,
    unsigned* __restrict__ M)
{
    __shared__ unsigned hist[NBUCK];
    const int r = hb / NCH_PER_R, bx = hb % NCH_PER_R;
    const int* ei = (r == 0) ? ei0 : ((r == 1) ? ei1 : ei2);
    const int t = threadIdx.x;
    for (int i = t; i < NBUCK; i += 256) hist[i] = 0;
    __syncthreads();
    const int e0 = bx * CHUNK_E;
    const int e1 = (e0 + CHUNK_E < EE) ? e0 + CHUNK_E : EE;
    for (int e = e0 + t; e < e1; e += 256) {
        int idx = r * NN + ei[EE + e];
        atomicAdd(&hist[idx >> 8], 1u);
    }
    __syncthreads();
    const int c = r * NCH_PER_R + bx;
    for (int i = t; i < NBUCK; i += 256) M[(size_t)i * NCH + c] = hist[i];
}

// ---------------- fused: gemm L1 (blocks 0..1562) + chunk_hist (blocks 1563..) ----------------
__global__ __launch_bounds__(256) void fused_prep(
    const float* __restrict__ x, const __half* __restrict__ Wp1,
    const float* __restrict__ as1, const float* __restrict__ ad1,
    __half* __restrict__ h, float* __restrict__ als, float* __restrict__ ald,
    const int* __restrict__ ei0, const int* __restrict__ ei1, const int* __restrict__ ei2,
    unsigned* __restrict__ M)
{
    if ((int)blockIdx.x < GEMM_BLKS)
        gemm_body<DIN, float>(blockIdx.x, x, Wp1, as1, ad1, h, als, ald);
    else
        hist_body(blockIdx.x - GEMM_BLKS, ei0, ei1, ei2, M);
}

// standalone gemm for layer 2
template<int K, typename AT>
__global__ __launch_bounds__(256) void gemm_mfma2(
    const AT* __restrict__ xin, const __half* __restrict__ Wp,
    const float* __restrict__ asrc, const float* __restrict__ adst,
    __half* __restrict__ h, float* __restrict__ als, float* __restrict__ ald)
{
    gemm_body<K, AT>(blockIdx.x, xin, Wp, asrc, adst, h, als, ald);
}

// ---------------- cooperative CSR finish: scan -> scan_add -> scatter -> bucket_build ----------------
// One dispatch, grid.sync() between phases. Grid = NCH (735) blocks; LDS union 35.8KB
// -> 4 blocks/CU -> 1024 co-resident >= 735 (cooperative-safe).
__global__ __launch_bounds__(256) void csr_finish(
    const int* __restrict__ ei0, const int* __restrict__ ei1, const int* __restrict__ ei2,
    unsigned* __restrict__ M, unsigned* __restrict__ bsum,
    unsigned* __restrict__ packed, unsigned* __restrict__ off)
{
    __shared__ unsigned smem[2 * BCAP + 3 * BSEG];   // 8960 u32 = 35.8KB, aliased per phase
    cg::grid_group grid = cg::this_grid();
    const int t = threadIdx.x;
    const int nb = gridDim.x;      // NCH = 735

    // ---- phase A: per-chunk exclusive scan of M (grid-stride over NSCB) ----
    {
        unsigned* tsum = smem;
        for (int b = blockIdx.x; b < NSCB; b += nb) {
            __syncthreads();                         // smem reuse guard
            const int i0 = b * SCAN_CHUNK + t * 4;
            unsigned v[4];
#pragma unroll
            for (int k = 0; k < 4; ++k) v[k] = (i0 + k < MT) ? M[i0 + k] : 0u;
            unsigned run = 0;
#pragma unroll
            for (int k = 0; k < 4; ++k) { unsigned x = v[k]; v[k] = run; run += x; }
            tsum[t] = run;
            __syncthreads();
            unsigned val = run;
            for (int d = 1; d < 256; d <<= 1) {
                unsigned add = (t >= d) ? tsum[t - d] : 0u;
                __syncthreads();
                val += add;
                tsum[t] = val;
                __syncthreads();
            }
            unsigned texcl = val - run;
            if (t == 255) bsum[b] = val;
#pragma unroll
            for (int k = 0; k < 4; ++k)
                if (i0 + k < MT) M[i0 + k] = texcl + v[k];
        }
    }
    grid.sync();

    // ---- phase B: add bsum prefix (each block recomputes its own prefix) ----
    {
        unsigned* red = smem;
        for (int b = blockIdx.x; b < NSCB; b += nb) {
            __syncthreads();
            unsigned part = 0;
            for (int j = t; j < b; j += 256) part += bsum[j];
            red[t] = part;
            __syncthreads();
            for (int s = 128; s; s >>= 1) {
                if (t < s) red[t] += red[t + s];
                __syncthreads();
            }
            unsigned P = red[0];
            const int i0 = b * SCAN_CHUNK + t * 4;
#pragma unroll
            for (int k = 0; k < 4; ++k)
                if (i0 + k < MT) M[i0 + k] += P;
        }
    }
    grid.sync();

    // ---- phase C: chunk_scatter (1:1, gridDim == NCH) ----
    {
        unsigned* cur = smem;      // NBUCK entries
        const int hb = blockIdx.x;
        const int r = hb / NCH_PER_R, bx = hb % NCH_PER_R;
        const int* ei = (r == 0) ? ei0 : ((r == 1) ? ei1 : ei2);
        __syncthreads();
        for (int i = t; i < NBUCK; i += 256) cur[i] = M[(size_t)i * NCH + hb];
        __syncthreads();
        const int e0 = bx * CHUNK_E;
        const int e1 = (e0 + CHUNK_E < EE) ? e0 + CHUNK_E : EE;
        for (int e = e0 + t; e < e1; e += 256) {
            int src = ei[e];
            int idx = r * NN + ei[EE + e];
            unsigned pos = atomicAdd(&cur[idx >> 8], 1u);
            packed[pos] = (unsigned)src | ((unsigned)(idx & 255) << 24);
        }
    }
    grid.sync();

    // ---- phase D: bucket_build (grid-stride over NBUCK) ----
    {
        unsigned* sp   = smem;
        unsigned* ssrc = smem + BCAP;
        unsigned* scnt = smem + 2 * BCAP;
        unsigned* scur = smem + 2 * BCAP + BSEG;
        unsigned* ts2  = smem + 2 * BCAP + 2 * BSEG;
        for (int b = blockIdx.x; b < NBUCK; b += nb) {
            __syncthreads();
            const unsigned base = M[(size_t)b * NCH];
            const unsigned next = (b + 1 < NBUCK) ? M[(size_t)(b + 1) * NCH] : (unsigned)((size_t)RRR * EE);
            int cnt = (int)(next - base);
            if (cnt > BCAP) cnt = BCAP;
            for (int i = t; i < cnt; i += 256) sp[i] = packed[base + i];
            scnt[t] = 0;
            __syncthreads();
            for (int i = t; i < cnt; i += 256) atomicAdd(&scnt[sp[i] >> 24], 1u);
            __syncthreads();
            unsigned v = scnt[t];
            ts2[t] = v;
            __syncthreads();
            unsigned val = v;
            for (int d = 1; d < 256; d <<= 1) {
                unsigned add = (t >= d) ? ts2[t - d] : 0u;
                __syncthreads();
                val += add;
                ts2[t] = val;
                __syncthreads();
            }
            unsigned excl = val - v;
            scur[t] = excl;
            const int segs = (NR - b * BSEG < BSEG) ? (NR - b * BSEG) : BSEG;
            if (t < segs) off[b * BSEG + t] = base + excl;
            __syncthreads();
            for (int i = t; i < cnt; i += 256) {
                unsigned p = sp[i];
                unsigned pos = atomicAdd(&scur[p >> 24], 1u);
                ssrc[pos] = p & 0x00FFFFFFu;
            }
            __syncthreads();
            for (int i = t; i < cnt; i += 256) packed[base + i] = ssrc[i];
        }
    }
}

// ---------------- aggregation v10: 2 nodes/wave, no-max softmax, pre-normalized p ----------------
template<bool L1>
__global__ __launch_bounds__(256) void aggregate10(
    const int* __restrict__ csr_src, const unsigned* __restrict__ off,
    const __half* __restrict__ h,    // [R, NN, 64] fp16
    const float* __restrict__ als, const float* __restrict__ ald,  // [R, NN]
    const float* __restrict__ bsum3, // [64] = (sum_r bias[r]) / 3
    float* __restrict__ outp,        // [NN, 64] fp32 (L2)
    __half* __restrict__ outH)       // [NN, 64] fp16 (L1)
{
    __shared__ float sbuf[4][64];    // fallback-path layout conversion only
    const int wid = threadIdx.x >> 6;
    const int lane = threadIdx.x & 63;
    const int nh = lane >> 5;        // node half 0/1
    const int l31 = lane & 31;
    const int sub = l31 >> 4;        // 0/1
    const int fc = l31 & 15;         // feature chunk (4 floats)
    const int node = blockIdx.x * 8 + wid * 2 + nh;   // 8 nodes/block; 12500*8 = NN exact

    unsigned start[RRR]; int cnt[RRR]; float aldv[RRR];
    int maxcnt = 0;
#pragma unroll
    for (int r = 0; r < RRR; ++r) {
        int idx = r * NN + node;
        unsigned s = off[idx];
        unsigned e = (idx == NR - 1) ? (unsigned)((size_t)RRR * EE) : off[idx + 1];
        start[r] = s; cnt[r] = (int)(e - s); aldv[r] = ald[idx];
        if (cnt[r] > maxcnt) maxcnt = cnt[r];
    }

    float4 total = make_float4(0.f, 0.f, 0.f, 0.f);

    if (__all(maxcnt <= 32)) {
        // ---- phase 1: logits -> exp -> den -> pre-normalized p (no max-reduce) ----
        int srcv[RRR]; float p[RRR], den[RRR];
#pragma unroll
        for (int r = 0; r < RRR; ++r) {
            bool act = l31 < cnt[r];
            int s_ = act ? csr_src[start[r] + l31] : 0;       // coalesced
            srcv[r] = s_;
            float sv = act ? (als[r * NN + s_] + aldv[r]) : -3.0e38f;
            float lr = (sv > 0.f) ? sv : SLOPE * sv;
            lr = fminf(lr, 60.f);         // overflow guard; never binds (logits ~N(0,1.4))
            p[r] = __expf(lr);            // pad lanes: exp(-6e37) == 0 exactly
            den[r] = dpp_allred_add16(p[r]);
        }
#pragma unroll
        for (int r = 0; r < RRR; ++r) den[r] += __shfl_xor(den[r], 16);
#pragma unroll
        for (int r = 0; r < RRR; ++r) {
            float inv = (cnt[r] > 0) ? 1.f / den[r] : 0.f;
            p[r] *= inv;                  // coefficient, already normalized
        }

        // ---- phase 2: per relation, 8-edge volleys (4 loads/lane), single acc ----
        float4 acc = make_float4(0.f, 0.f, 0.f, 0.f);
#pragma unroll
        for (int r = 0; r < RRR; ++r) {
            const __half* hr = h + (size_t)r * NN * DOUT;
            const int nq = (cnt[r] + 7) >> 3;
            for (int q = 0; q < nq; ++q) {
                const int base = q * 8;
                float pl[4]; int sl[4];
#pragma unroll
                for (int l = 0; l < 4; ++l) {
                    int e = base + l * 2 + sub;         // <= 31 for cnt <= 32
                    pl[l] = __shfl(p[r], nh * 32 + e);
                    sl[l] = __shfl(srcv[r], nh * 32 + e);
                }
                uint2 rl[4];
#pragma unroll
                for (int l = 0; l < 4; ++l)
                    rl[l] = *(const uint2*)(hr + (size_t)sl[l] * DOUT + fc * 4);
#pragma unroll
                for (int l = 0; l < 4; ++l) {
                    float2 f01 = __half22float2(*(const __half2*)&rl[l].x);
                    float2 f23 = __half22float2(*(const __half2*)&rl[l].y);
                    acc.x = fmaf(pl[l], f01.x, acc.x);
                    acc.y = fmaf(pl[l], f01.y, acc.y);
                    acc.z = fmaf(pl[l], f23.x, acc.z);
                    acc.w = fmaf(pl[l], f23.y, acc.w);
                }
            }
        }
        // ONE sub-reduce (2 subs): xor16 stays within each 32-group
        acc.x += __shfl_xor(acc.x, 16); acc.y += __shfl_xor(acc.y, 16);
        acc.z += __shfl_xor(acc.z, 16); acc.w += __shfl_xor(acc.w, 16);
        total = acc;
    } else {
        // ---- rare fallback: both nodes serially, full 64-lane online softmax ----
        for (int nn = 0; nn < 2; ++nn) {
            int node2 = blockIdx.x * 8 + wid * 2 + nn;
            float totalS = 0.f;
#pragma unroll
            for (int r = 0; r < RRR; ++r) {
                int idx = r * NN + node2;
                unsigned s2 = off[idx];
                unsigned e2 = (idx == NR - 1) ? (unsigned)((size_t)RRR * EE) : off[idx + 1];
                int c2 = (int)(e2 - s2);
                if (c2 <= 0) continue;
                float aldv2 = ald[idx];
                const __half* hr = h + (size_t)r * NN * DOUT;
                const float* alsr = als + (size_t)r * NN;
                float m = -3.4e38f, den = 0.f, accv = 0.f;
                for (int t0 = 0; t0 < c2; t0 += 64) {
                    int j = t0 + lane;
                    bool act = (j < c2);
                    int src = 0;
                    float lrv = -3.4e38f;
                    if (act) {
                        src = csr_src[s2 + j];
                        float sv = alsr[src] + aldv2;
                        lrv = (sv > 0.f) ? sv : SLOPE * sv;
                    }
                    float mt = lrv;
#pragma unroll
                    for (int o = 32; o; o >>= 1) mt = fmaxf(mt, __shfl_xor(mt, o));
                    float mnew = fmaxf(m, mt);
                    float scale = __expf(m - mnew);
                    den *= scale; accv *= scale; m = mnew;
                    float pp = act ? __expf(lrv - m) : 0.f;
                    float ps = pp;
#pragma unroll
                    for (int o = 32; o; o >>= 1) ps += __shfl_xor(ps, o);
                    den += ps;
                    int tcnt = c2 - t0; if (tcnt > 64) tcnt = 64;
                    for (int j2 = 0; j2 < tcnt; ++j2) {
                        int sj = __builtin_amdgcn_readlane(src, j2);
                        float pj = __int_as_float(__builtin_amdgcn_readlane(__float_as_int(pp), j2));
                        accv = fmaf(pj, __half2float(hr[(size_t)sj * DOUT + lane]), accv);
                    }
                }
                totalS += accv / den;
            }
            sbuf[wid][lane] = totalS;
            __builtin_amdgcn_s_waitcnt(0);
            if (nh == nn) total = *(const float4*)&sbuf[wid][fc * 4];
            __builtin_amdgcn_s_waitcnt(0);
        }
    }

    // ---- epilogue: v = total/3 + (sum_r bias)/3 ----
    float4 bb = *(const float4*)(bsum3 + fc * 4);
    float4 v;
    v.x = fmaf(total.x, 1.f / 3.f, bb.x);
    v.y = fmaf(total.y, 1.f / 3.f, bb.y);
    v.z = fmaf(total.z, 1.f / 3.f, bb.z);
    v.w = fmaf(total.w, 1.f / 3.f, bb.w);
    if (L1) {
        float ss = v.x * v.x + v.y * v.y + v.z * v.z + v.w * v.w;
        ss = dpp_allred_add16(ss);     // 16-lane fc-group reduce (within row)
        float di = 1.f / fmaxf(sqrtf(ss), 1e-12f);
        v.x = fmaxf(v.x * di, 0.f);
        v.y = fmaxf(v.y * di, 0.f);
        v.z = fmaxf(v.z * di, 0.f);
        v.w = fmaxf(v.w * di, 0.f);
        if (sub == 0) {
            __half2* o2 = (__half2*)(outH + (size_t)node * DOUT + fc * 4);
            o2[0] = __floats2half2_rn(v.x, v.y);
            o2[1] = __floats2half2_rn(v.z, v.w);
        }
    } else {
        if (sub == 0) *(float4*)(outp + (size_t)node * DOUT + fc * 4) = v;
    }
}

// ---------------- launch ----------------
extern "C" void kernel_launch(void* const* d_in, const int* in_sizes, int n_in,
                              void* d_out, int out_size, void* d_ws, size_t ws_size,
                              hipStream_t stream) {
    const float* x   = (const float*)d_in[0];
    const int* ei0   = (const int*)d_in[1];
    const int* ei1   = (const int*)d_in[2];
    const int* ei2   = (const int*)d_in[3];
    const float* W1  = (const float*)d_in[4];
    const float* as1 = (const float*)d_in[5];
    const float* ad1 = (const float*)d_in[6];
    const float* b1  = (const float*)d_in[7];
    const float* W2  = (const float*)d_in[8];
    const float* as2 = (const float*)d_in[9];
    const float* ad2 = (const float*)d_in[10];
    const float* b2  = (const float*)d_in[11];
    float* out = (float*)d_out;

    // workspace carve-up (4B units), ~72 MB total
    float* ws = (float*)d_ws;
    size_t off_u = 0;
    __half* h       = (__half*)(ws + off_u); off_u += (size_t)RRR * NN * DOUT / 2;  // 9.6M floats
    float* als      = ws + off_u; off_u += (size_t)RRR * NN;
    float* ald      = ws + off_u; off_u += (size_t)RRR * NN;
    unsigned* packed= (unsigned*)(ws + off_u); off_u += (size_t)RRR * EE; // 3M; becomes csr_src
    unsigned* off   = (unsigned*)(ws + off_u); off_u += NR;
    __half* hmid_h  = (__half*)(ws + off_u); off_u += (size_t)NN * DOUT / 2;  // 3.2M floats
    __half* Wp1     = (__half*)(ws + off_u); off_u += (3 * 16 * 512) / 2;
    __half* Wp2     = (__half*)(ws + off_u); off_u += (3 * 8 * 512) / 2;
    float* bs1      = ws + off_u; off_u += 64;
    float* bs2      = ws + off_u; off_u += 64;
    unsigned* M     = (unsigned*)(ws + off_u); off_u += MT;
    unsigned* bsum  = (unsigned*)(ws + off_u); off_u += NSCB + 8;

    dim3 blk(256);
    int gA = (NN + 7) / 8;            // 12500 (2 nodes per wave)

    // pack first (gemm in fused_prep reads Wp1)
    pack_W<<<3, blk, 0, stream>>>(W1, W2, b1, b2, Wp1, Wp2, bs1, bs2);

    // fused: gemm L1 (1563 blocks) || chunk_hist (735 blocks) — independent work
    fused_prep<<<GEMM_BLKS + NCH, blk, 0, stream>>>(
        x, Wp1, as1, ad1, h, als, ald, ei0, ei1, ei2, M);

    // CSR build completion: one cooperative dispatch (scan -> add -> scatter -> build)
    {
        void* args[] = { (void*)&ei0, (void*)&ei1, (void*)&ei2,
                         (void*)&M, (void*)&bsum, (void*)&packed, (void*)&off };
        hipLaunchCooperativeKernel((const void*)csr_finish, dim3(NCH), blk, args, 0, stream);
    }
    const int* csr_src = (const int*)packed;

    // ---- layer 1 aggregate ----
    aggregate10<true><<<gA, blk, 0, stream>>>(csr_src, off, h, als, ald, bs1, out, hmid_h);

    // ---- layer 2 ----
    gemm_mfma2<DOUT, __half><<<GEMM_BLKS, blk, 0, stream>>>(hmid_h, Wp2, as2, ad2, h, als, ald);
    aggregate10<false><<<gA, blk, 0, stream>>>(csr_src, off, h, als, ald, bs2, out, hmid_h);
}

// Round 17
// 256.556 us; speedup vs baseline: 2.1633x; 2.1633x over previous
//
#include <hip/hip_runtime.h>
#include <hip/hip_bf16.h>
#include <hip/hip_fp16.h>
#include <math.h>

constexpr int NN = 100000;
constexpr int EE = 1000000;
constexpr int RRR = 3;
constexpr int DIN = 128;
constexpr int DOUT = 64;
constexpr float SLOPE = 0.2f;
constexpr int NR = RRR * NN;                    // 300000 segments (relation-major)
constexpr int BSEG = 256;                       // segments per bucket
constexpr int NBUCK = (NR + BSEG - 1) / BSEG;   // 1172
constexpr int BCAP = 4096;                      // max edges/bucket
constexpr int CHUNK_E = 4096;                   // edges per chunk-block
constexpr int NCH_PER_R = (EE + CHUNK_E - 1) / CHUNK_E;   // 245
constexpr int NCH = RRR * NCH_PER_R;            // 735
constexpr int MT = NBUCK * NCH;                 // 861420
constexpr int SCAN_CHUNK = 1024;
constexpr int NSCB = (MT + SCAN_CHUNK - 1) / SCAN_CHUNK;  // 842
constexpr int GEMM_BLKS = (NN + 63) / 64;       // 1563

using f16x8 = __attribute__((ext_vector_type(8))) _Float16;
using f32x4 = __attribute__((ext_vector_type(4))) float;

// ---- DPP helpers: data movement on VALU pipe (no LDS round trip) ----
template<int CTRL>
__device__ __forceinline__ float dppf(float v) {
    return __int_as_float(__builtin_amdgcn_update_dpp(
        __float_as_int(v), __float_as_int(v), CTRL, 0xf, 0xf, false));
}
__device__ __forceinline__ float dpp_allred_add16(float v) {
    v += dppf<0xB1>(v);    // quad_perm xor1
    v += dppf<0x4E>(v);    // quad_perm xor2
    v += dppf<0x141>(v);   // row_half_mirror
    v += dppf<0x140>(v);   // row_mirror
    return v;
}

// ---------------- W -> MFMA B-fragment pack (fp16) + bias-sum precompute ----------------
__global__ __launch_bounds__(256) void pack_W(
    const float* __restrict__ W1, const float* __restrict__ W2,
    const float* __restrict__ b1, const float* __restrict__ b2,
    __half* __restrict__ Wp1, __half* __restrict__ Wp2,
    float* __restrict__ bs1, float* __restrict__ bs2)
{
    int r = blockIdx.x;  // 0..2
    for (int i = threadIdx.x; i < 4 * 4 * 512; i += 256) {    // W1: KS=4
        int j = i & 7, lane = (i >> 3) & 63, nt = (i >> 9) & 3, ks = i >> 11;
        int k = ks * 32 + (lane >> 4) * 8 + j, c = nt * 16 + (lane & 15);
        Wp1[((size_t)r * 16 + ks * 4 + nt) * 512 + lane * 8 + j] = __float2half(W1[(r * DIN + k) * 64 + c]);
    }
    for (int i = threadIdx.x; i < 2 * 4 * 512; i += 256) {    // W2: KS=2
        int j = i & 7, lane = (i >> 3) & 63, nt = (i >> 9) & 3, ks = i >> 11;
        int k = ks * 32 + (lane >> 4) * 8 + j, c = nt * 16 + (lane & 15);
        Wp2[((size_t)r * 8 + ks * 4 + nt) * 512 + lane * 8 + j] = __float2half(W2[(r * DOUT + k) * 64 + c]);
    }
    if (r == 0) {
        for (int c = threadIdx.x; c < 64; c += 256) {
            bs1[c] = (b1[c] + b1[64 + c] + b1[128 + c]) * (1.f / 3.f);
            bs2[c] = (b2[c] + b2[64 + c] + b2[128 + c]) * (1.f / 3.f);
        }
    }
}

// ---------------- shared GEMM body (MFMA, all 3 relations per block) ----------------
template<int K, typename AT>
__device__ __forceinline__ void gemm_body(
    int gbid,                        // gemm block id: rows gbid*64..+63
    const AT* __restrict__ xin,      // [NN, K]
    const __half* __restrict__ Wp,   // packed [R][K/32][4][512]
    const float* __restrict__ asrc, const float* __restrict__ adst,  // [R,64]
    __half* __restrict__ h,          // [R, NN, 64] fp16
    float* __restrict__ als, float* __restrict__ ald)                // [R, NN]
{
    constexpr int KS = K / 32;
    __shared__ float outb[64 * 65];
    const int t = threadIdx.x;
    const int lane = t & 63;
    const int w = t >> 6;
    const int row0 = gbid * 64;

    const int kgrp = lane >> 4;                  // 0..3
    const int l15 = lane & 15;
    int arow = row0 + w * 16 + l15; if (arow >= NN) arow = NN - 1;   // tail clamp (loads only)

    // ---- load A fragments once ----
    f16x8 a[KS];
    if constexpr (sizeof(AT) == 2) {
        const __half* ab = (const __half*)xin + (size_t)arow * K + kgrp * 8;
#pragma unroll
        for (int ks = 0; ks < KS; ++ks) a[ks] = *(const f16x8*)(ab + ks * 32);
    } else {
        const float* ab = (const float*)xin + (size_t)arow * K + kgrp * 8;
#pragma unroll
        for (int ks = 0; ks < KS; ++ks) {
            float4 lo = *(const float4*)(ab + ks * 32);
            float4 hi = *(const float4*)(ab + ks * 32 + 4);
            union { f16x8 v; __half2 p[4]; } u;
            u.p[0] = __floats2half2_rn(lo.x, lo.y);
            u.p[1] = __floats2half2_rn(lo.z, lo.w);
            u.p[2] = __floats2half2_rn(hi.x, hi.y);
            u.p[3] = __floats2half2_rn(hi.z, hi.w);
            a[ks] = u.v;
        }
    }

    const int nrows = (NN - row0 < 64) ? (NN - row0) : 64;

#pragma unroll
    for (int r = 0; r < RRR; ++r) {
        const __half* wbase = Wp + ((size_t)r * KS * 4) * 512 + lane * 8;
        f32x4 acc[4] = {};
#pragma unroll
        for (int ks = 0; ks < KS; ++ks) {
#pragma unroll
            for (int nt = 0; nt < 4; ++nt) {
                f16x8 b = *(const f16x8*)(wbase + (size_t)(ks * 4 + nt) * 512);
                acc[nt] = __builtin_amdgcn_mfma_f32_16x16x32_f16(a[ks], b, acc[nt], 0, 0, 0);
            }
        }

        // als/ald: lane holds cols {l15+16*nt} of rows row0+w*16+kgrp*4+i
        {
            float ps[4] = {0.f, 0.f, 0.f, 0.f}, pd[4] = {0.f, 0.f, 0.f, 0.f};
#pragma unroll
            for (int nt = 0; nt < 4; ++nt) {
                int c = l15 + 16 * nt;
                float a_ = asrc[r * 64 + c], d_ = adst[r * 64 + c];
#pragma unroll
                for (int i = 0; i < 4; ++i) {
                    ps[i] = fmaf(acc[nt][i], a_, ps[i]);
                    pd[i] = fmaf(acc[nt][i], d_, pd[i]);
                }
            }
#pragma unroll
            for (int o = 8; o; o >>= 1) {
#pragma unroll
                for (int i = 0; i < 4; ++i) {
                    ps[i] += __shfl_xor(ps[i], o);
                    pd[i] += __shfl_xor(pd[i], o);
                }
            }
            if (l15 == 0) {
#pragma unroll
                for (int i = 0; i < 4; ++i) {
                    int row = row0 + w * 16 + kgrp * 4 + i;
                    if (row < NN) { als[r * NN + row] = ps[i]; ald[r * NN + row] = pd[i]; }
                }
            }
        }

        // stage C to LDS, then coalesced fp16 write
#pragma unroll
        for (int nt = 0; nt < 4; ++nt)
#pragma unroll
            for (int i = 0; i < 4; ++i)
                outb[(w * 16 + kgrp * 4 + i) * 65 + l15 + 16 * nt] = acc[nt][i];
        __syncthreads();

        __half2* h2 = (__half2*)(h + ((size_t)r * NN + row0) * 64);
        for (int idx = t; idx < nrows * 32; idx += 256) {
            int row = idx >> 5, cc = idx & 31;
            h2[row * 32 + cc] = __floats2half2_rn(outb[row * 65 + cc * 2], outb[row * 65 + cc * 2 + 1]);
        }
        __syncthreads();
    }
}

__device__ __forceinline__ void hist_body(
    int hb,                          // hist block id 0..NCH-1
    const int* __restrict__ ei0, const int* __restrict__ ei1, const int* __restrict__ ei2,
    unsigned* __restrict__ M)
{
    __shared__ unsigned hist[NBUCK];
    const int r = hb / NCH_PER_R, bx = hb % NCH_PER_R;
    const int* ei = (r == 0) ? ei0 : ((r == 1) ? ei1 : ei2);
    const int t = threadIdx.x;
    for (int i = t; i < NBUCK; i += 256) hist[i] = 0;
    __syncthreads();
    const int e0 = bx * CHUNK_E;
    const int e1 = (e0 + CHUNK_E < EE) ? e0 + CHUNK_E : EE;
    for (int e = e0 + t; e < e1; e += 256) {
        int idx = r * NN + ei[EE + e];
        atomicAdd(&hist[idx >> 8], 1u);
    }
    __syncthreads();
    const int c = r * NCH_PER_R + bx;
    for (int i = t; i < NBUCK; i += 256) M[(size_t)i * NCH + c] = hist[i];
}

// ---------------- fused: gemm L1 (blocks 0..1562) + chunk_hist (blocks 1563..) ----------------
__global__ __launch_bounds__(256) void fused_prep(
    const float* __restrict__ x, const __half* __restrict__ Wp1,
    const float* __restrict__ as1, const float* __restrict__ ad1,
    __half* __restrict__ h, float* __restrict__ als, float* __restrict__ ald,
    const int* __restrict__ ei0, const int* __restrict__ ei1, const int* __restrict__ ei2,
    unsigned* __restrict__ M)
{
    if ((int)blockIdx.x < GEMM_BLKS)
        gemm_body<DIN, float>(blockIdx.x, x, Wp1, as1, ad1, h, als, ald);
    else
        hist_body(blockIdx.x - GEMM_BLKS, ei0, ei1, ei2, M);
}

// standalone gemm for layer 2
template<int K, typename AT>
__global__ __launch_bounds__(256) void gemm_mfma2(
    const AT* __restrict__ xin, const __half* __restrict__ Wp,
    const float* __restrict__ asrc, const float* __restrict__ adst,
    __half* __restrict__ h, float* __restrict__ als, float* __restrict__ ald)
{
    gemm_body<K, AT>(blockIdx.x, xin, Wp, asrc, adst, h, als, ald);
}

// ---------------- CSR build scans ----------------
__global__ __launch_bounds__(256) void scan_block(unsigned* __restrict__ data, unsigned* __restrict__ bsum)
{
    __shared__ unsigned tsum[256];
    const int base = blockIdx.x * SCAN_CHUNK;
    const int t = threadIdx.x;
    const int i0 = base + t * 4;
    unsigned v[4];
#pragma unroll
    for (int k = 0; k < 4; ++k) v[k] = (i0 + k < MT) ? data[i0 + k] : 0u;
    unsigned run = 0;
#pragma unroll
    for (int k = 0; k < 4; ++k) { unsigned x = v[k]; v[k] = run; run += x; }
    tsum[t] = run;
    __syncthreads();
    unsigned val = run;
    for (int d = 1; d < 256; d <<= 1) {
        unsigned add = (t >= d) ? tsum[t - d] : 0u;
        __syncthreads();
        val += add;
        tsum[t] = val;
        __syncthreads();
    }
    unsigned texcl = val - run;
    if (t == 255) bsum[blockIdx.x] = val;
#pragma unroll
    for (int k = 0; k < 4; ++k)
        if (i0 + k < MT) data[i0 + k] = texcl + v[k];
}

// fused scan_bsums + add_off: each block recomputes its own bsum prefix
__global__ __launch_bounds__(256) void scan_add(unsigned* __restrict__ data, const unsigned* __restrict__ bsum)
{
    __shared__ unsigned red[256];
    const int b = blockIdx.x, t = threadIdx.x;
    unsigned part = 0;
    for (int j = t; j < b; j += 256) part += bsum[j];
    red[t] = part;
    __syncthreads();
    for (int s = 128; s; s >>= 1) {
        if (t < s) red[t] += red[t + s];
        __syncthreads();
    }
    unsigned P = red[0];
    const int i0 = b * SCAN_CHUNK + t * 4;
#pragma unroll
    for (int k = 0; k < 4; ++k)
        if (i0 + k < MT) data[i0 + k] += P;
}

__global__ __launch_bounds__(256) void chunk_scatter(
    const int* __restrict__ ei0, const int* __restrict__ ei1, const int* __restrict__ ei2,
    const unsigned* __restrict__ Ms, unsigned* __restrict__ packed)
{
    __shared__ unsigned cur[NBUCK];
    const int r = blockIdx.y, bx = blockIdx.x;
    const int* ei = (r == 0) ? ei0 : ((r == 1) ? ei1 : ei2);
    const int t = threadIdx.x;
    const int c = r * NCH_PER_R + bx;
    for (int i = t; i < NBUCK; i += 256) cur[i] = Ms[(size_t)i * NCH + c];
    __syncthreads();
    const int e0 = bx * CHUNK_E;
    const int e1 = (e0 + CHUNK_E < EE) ? e0 + CHUNK_E : EE;
    for (int e = e0 + t; e < e1; e += 256) {
        int src = ei[e];
        int idx = r * NN + ei[EE + e];
        unsigned pos = atomicAdd(&cur[idx >> 8], 1u);
        packed[pos] = (unsigned)src | ((unsigned)(idx & 255) << 24);
    }
}

__global__ __launch_bounds__(256) void bucket_build(
    unsigned* __restrict__ packed,        // in: pairs; out: csr_src (same buffer)
    const unsigned* __restrict__ Ms,      // scanned matrix: Ms[b*NCH] = bucket base
    unsigned* __restrict__ off)           // [NR]
{
    __shared__ unsigned sp[BCAP];
    __shared__ unsigned ssrc[BCAP];
    __shared__ unsigned scnt[BSEG];
    __shared__ unsigned scur[BSEG];
    __shared__ unsigned tsum[BSEG];
    const int b = blockIdx.x;
    const int t = threadIdx.x;
    const unsigned base = Ms[(size_t)b * NCH];
    const unsigned next = (b + 1 < NBUCK) ? Ms[(size_t)(b + 1) * NCH] : (unsigned)((size_t)RRR * EE);
    int cnt = (int)(next - base);
    if (cnt > BCAP) cnt = BCAP;
    for (int i = t; i < cnt; i += 256) sp[i] = packed[base + i];
    scnt[t] = 0;
    __syncthreads();
    for (int i = t; i < cnt; i += 256) atomicAdd(&scnt[sp[i] >> 24], 1u);
    __syncthreads();
    unsigned v = scnt[t];
    tsum[t] = v;
    __syncthreads();
    unsigned val = v;
    for (int d = 1; d < 256; d <<= 1) {
        unsigned add = (t >= d) ? tsum[t - d] : 0u;
        __syncthreads();
        val += add;
        tsum[t] = val;
        __syncthreads();
    }
    unsigned excl = val - v;
    scur[t] = excl;
    const int segs = (NR - b * BSEG < BSEG) ? (NR - b * BSEG) : BSEG;
    if (t < segs) off[b * BSEG + t] = base + excl;
    __syncthreads();
    for (int i = t; i < cnt; i += 256) {
        unsigned p = sp[i];
        unsigned pos = atomicAdd(&scur[p >> 24], 1u);
        ssrc[pos] = p & 0x00FFFFFFu;
    }
    __syncthreads();
    for (int i = t; i < cnt; i += 256) packed[base + i] = ssrc[i];
}

// ---------------- aggregation v10: 2 nodes/wave, no-max softmax, pre-normalized p ----------------
template<bool L1>
__global__ __launch_bounds__(256) void aggregate10(
    const int* __restrict__ csr_src, const unsigned* __restrict__ off,
    const __half* __restrict__ h,    // [R, NN, 64] fp16
    const float* __restrict__ als, const float* __restrict__ ald,  // [R, NN]
    const float* __restrict__ bsum3, // [64] = (sum_r bias[r]) / 3
    float* __restrict__ outp,        // [NN, 64] fp32 (L2)
    __half* __restrict__ outH)       // [NN, 64] fp16 (L1)
{
    __shared__ float sbuf[4][64];    // fallback-path layout conversion only
    const int wid = threadIdx.x >> 6;
    const int lane = threadIdx.x & 63;
    const int nh = lane >> 5;        // node half 0/1
    const int l31 = lane & 31;
    const int sub = l31 >> 4;        // 0/1
    const int fc = l31 & 15;         // feature chunk (4 floats)
    const int node = blockIdx.x * 8 + wid * 2 + nh;   // 8 nodes/block; 12500*8 = NN exact

    unsigned start[RRR]; int cnt[RRR]; float aldv[RRR];
    int maxcnt = 0;
#pragma unroll
    for (int r = 0; r < RRR; ++r) {
        int idx = r * NN + node;
        unsigned s = off[idx];
        unsigned e = (idx == NR - 1) ? (unsigned)((size_t)RRR * EE) : off[idx + 1];
        start[r] = s; cnt[r] = (int)(e - s); aldv[r] = ald[idx];
        if (cnt[r] > maxcnt) maxcnt = cnt[r];
    }

    float4 total = make_float4(0.f, 0.f, 0.f, 0.f);

    if (__all(maxcnt <= 32)) {
        // ---- phase 1: logits -> exp -> den -> pre-normalized p (no max-reduce) ----
        int srcv[RRR]; float p[RRR], den[RRR];
#pragma unroll
        for (int r = 0; r < RRR; ++r) {
            bool act = l31 < cnt[r];
            int s_ = act ? csr_src[start[r] + l31] : 0;       // coalesced
            srcv[r] = s_;
            float sv = act ? (als[r * NN + s_] + aldv[r]) : -3.0e38f;
            float lr = (sv > 0.f) ? sv : SLOPE * sv;
            lr = fminf(lr, 60.f);         // overflow guard; never binds (logits ~N(0,1.4))
            p[r] = __expf(lr);            // pad lanes: exp(-6e37) == 0 exactly
            den[r] = dpp_allred_add16(p[r]);
        }
#pragma unroll
        for (int r = 0; r < RRR; ++r) den[r] += __shfl_xor(den[r], 16);
#pragma unroll
        for (int r = 0; r < RRR; ++r) {
            float inv = (cnt[r] > 0) ? 1.f / den[r] : 0.f;
            p[r] *= inv;                  // coefficient, already normalized
        }

        // ---- phase 2: per relation, 8-edge volleys (4 loads/lane), single acc ----
        float4 acc = make_float4(0.f, 0.f, 0.f, 0.f);
#pragma unroll
        for (int r = 0; r < RRR; ++r) {
            const __half* hr = h + (size_t)r * NN * DOUT;
            const int nq = (cnt[r] + 7) >> 3;
            for (int q = 0; q < nq; ++q) {
                const int base = q * 8;
                float pl[4]; int sl[4];
#pragma unroll
                for (int l = 0; l < 4; ++l) {
                    int e = base + l * 2 + sub;         // <= 31 for cnt <= 32
                    pl[l] = __shfl(p[r], nh * 32 + e);
                    sl[l] = __shfl(srcv[r], nh * 32 + e);
                }
                uint2 rl[4];
#pragma unroll
                for (int l = 0; l < 4; ++l)
                    rl[l] = *(const uint2*)(hr + (size_t)sl[l] * DOUT + fc * 4);
#pragma unroll
                for (int l = 0; l < 4; ++l) {
                    float2 f01 = __half22float2(*(const __half2*)&rl[l].x);
                    float2 f23 = __half22float2(*(const __half2*)&rl[l].y);
                    acc.x = fmaf(pl[l], f01.x, acc.x);
                    acc.y = fmaf(pl[l], f01.y, acc.y);
                    acc.z = fmaf(pl[l], f23.x, acc.z);
                    acc.w = fmaf(pl[l], f23.y, acc.w);
                }
            }
        }
        // ONE sub-reduce (2 subs): xor16 stays within each 32-group
        acc.x += __shfl_xor(acc.x, 16); acc.y += __shfl_xor(acc.y, 16);
        acc.z += __shfl_xor(acc.z, 16); acc.w += __shfl_xor(acc.w, 16);
        total = acc;
    } else {
        // ---- rare fallback: both nodes serially, full 64-lane online softmax ----
        for (int nn = 0; nn < 2; ++nn) {
            int node2 = blockIdx.x * 8 + wid * 2 + nn;
            float totalS = 0.f;
#pragma unroll
            for (int r = 0; r < RRR; ++r) {
                int idx = r * NN + node2;
                unsigned s2 = off[idx];
                unsigned e2 = (idx == NR - 1) ? (unsigned)((size_t)RRR * EE) : off[idx + 1];
                int c2 = (int)(e2 - s2);
                if (c2 <= 0) continue;
                float aldv2 = ald[idx];
                const __half* hr = h + (size_t)r * NN * DOUT;
                const float* alsr = als + (size_t)r * NN;
                float m = -3.4e38f, den = 0.f, accv = 0.f;
                for (int t0 = 0; t0 < c2; t0 += 64) {
                    int j = t0 + lane;
                    bool act = (j < c2);
                    int src = 0;
                    float lrv = -3.4e38f;
                    if (act) {
                        src = csr_src[s2 + j];
                        float sv = alsr[src] + aldv2;
                        lrv = (sv > 0.f) ? sv : SLOPE * sv;
                    }
                    float mt = lrv;
#pragma unroll
                    for (int o = 32; o; o >>= 1) mt = fmaxf(mt, __shfl_xor(mt, o));
                    float mnew = fmaxf(m, mt);
                    float scale = __expf(m - mnew);
                    den *= scale; accv *= scale; m = mnew;
                    float pp = act ? __expf(lrv - m) : 0.f;
                    float ps = pp;
#pragma unroll
                    for (int o = 32; o; o >>= 1) ps += __shfl_xor(ps, o);
                    den += ps;
                    int tcnt = c2 - t0; if (tcnt > 64) tcnt = 64;
                    for (int j2 = 0; j2 < tcnt; ++j2) {
                        int sj = __builtin_amdgcn_readlane(src, j2);
                        float pj = __int_as_float(__builtin_amdgcn_readlane(__float_as_int(pp), j2));
                        accv = fmaf(pj, __half2float(hr[(size_t)sj * DOUT + lane]), accv);
                    }
                }
                totalS += accv / den;
            }
            sbuf[wid][lane] = totalS;
            __builtin_amdgcn_s_waitcnt(0);
            if (nh == nn) total = *(const float4*)&sbuf[wid][fc * 4];
            __builtin_amdgcn_s_waitcnt(0);
        }
    }

    // ---- epilogue: v = total/3 + (sum_r bias)/3 ----
    float4 bb = *(const float4*)(bsum3 + fc * 4);
    float4 v;
    v.x = fmaf(total.x, 1.f / 3.f, bb.x);
    v.y = fmaf(total.y, 1.f / 3.f, bb.y);
    v.z = fmaf(total.z, 1.f / 3.f, bb.z);
    v.w = fmaf(total.w, 1.f / 3.f, bb.w);
    if (L1) {
        float ss = v.x * v.x + v.y * v.y + v.z * v.z + v.w * v.w;
        ss = dpp_allred_add16(ss);     // 16-lane fc-group reduce (within row)
        float di = 1.f / fmaxf(sqrtf(ss), 1e-12f);
        v.x = fmaxf(v.x * di, 0.f);
        v.y = fmaxf(v.y * di, 0.f);
        v.z = fmaxf(v.z * di, 0.f);
        v.w = fmaxf(v.w * di, 0.f);
        if (sub == 0) {
            __half2* o2 = (__half2*)(outH + (size_t)node * DOUT + fc * 4);
            o2[0] = __floats2half2_rn(v.x, v.y);
            o2[1] = __floats2half2_rn(v.z, v.w);
        }
    } else {
        if (sub == 0) *(float4*)(outp + (size_t)node * DOUT + fc * 4) = v;
    }
}

// ---------------- launch ----------------
extern "C" void kernel_launch(void* const* d_in, const int* in_sizes, int n_in,
                              void* d_out, int out_size, void* d_ws, size_t ws_size,
                              hipStream_t stream) {
    const float* x   = (const float*)d_in[0];
    const int* ei0   = (const int*)d_in[1];
    const int* ei1   = (const int*)d_in[2];
    const int* ei2   = (const int*)d_in[3];
    const float* W1  = (const float*)d_in[4];
    const float* as1 = (const float*)d_in[5];
    const float* ad1 = (const float*)d_in[6];
    const float* b1  = (const float*)d_in[7];
    const float* W2  = (const float*)d_in[8];
    const float* as2 = (const float*)d_in[9];
    const float* ad2 = (const float*)d_in[10];
    const float* b2  = (const float*)d_in[11];
    float* out = (float*)d_out;

    // workspace carve-up (4B units), ~72 MB total
    float* ws = (float*)d_ws;
    size_t off_u = 0;
    __half* h       = (__half*)(ws + off_u); off_u += (size_t)RRR * NN * DOUT / 2;  // 9.6M floats
    float* als      = ws + off_u; off_u += (size_t)RRR * NN;
    float* ald      = ws + off_u; off_u += (size_t)RRR * NN;
    unsigned* packed= (unsigned*)(ws + off_u); off_u += (size_t)RRR * EE; // 3M; becomes csr_src
    unsigned* off   = (unsigned*)(ws + off_u); off_u += NR;
    __half* hmid_h  = (__half*)(ws + off_u); off_u += (size_t)NN * DOUT / 2;  // 3.2M floats
    __half* Wp1     = (__half*)(ws + off_u); off_u += (3 * 16 * 512) / 2;
    __half* Wp2     = (__half*)(ws + off_u); off_u += (3 * 8 * 512) / 2;
    float* bs1      = ws + off_u; off_u += 64;
    float* bs2      = ws + off_u; off_u += 64;
    unsigned* M     = (unsigned*)(ws + off_u); off_u += MT;
    unsigned* bsum  = (unsigned*)(ws + off_u); off_u += NSCB + 8;

    dim3 blk(256);
    dim3 gC(NCH_PER_R, RRR);          // 245 x 3
    int gA = (NN + 7) / 8;            // 12500 (2 nodes per wave)

    // pack first (gemm in fused_prep reads Wp1)
    pack_W<<<3, blk, 0, stream>>>(W1, W2, b1, b2, Wp1, Wp2, bs1, bs2);

    // fused: gemm L1 (1563 blocks) || chunk_hist (735 blocks) — independent work
    fused_prep<<<GEMM_BLKS + NCH, blk, 0, stream>>>(
        x, Wp1, as1, ad1, h, als, ald, ei0, ei1, ei2, M);

    // CSR build completion
    scan_block<<<NSCB, blk, 0, stream>>>(M, bsum);
    scan_add<<<NSCB, blk, 0, stream>>>(M, bsum);
    chunk_scatter<<<gC, blk, 0, stream>>>(ei0, ei1, ei2, M, packed);
    bucket_build<<<NBUCK, blk, 0, stream>>>(packed, M, off);
    const int* csr_src = (const int*)packed;

    // ---- layer 1 aggregate ----
    aggregate10<true><<<gA, blk, 0, stream>>>(csr_src, off, h, als, ald, bs1, out, hmid_h);

    // ---- layer 2 ----
    gemm_mfma2<DOUT, __half><<<GEMM_BLKS, blk, 0, stream>>>(hmid_h, Wp2, as2, ad2, h, als, ald);
    aggregate10<false><<<gA, blk, 0, stream>>>(csr_src, off, h, als, ald, bs2, out, hmid_h);
}